// Round 2
// baseline (499.697 us; speedup 1.0000x reference)
//
#include <hip/hip_runtime.h>

// Problem constants (fixed by the reference): 131072 rows x 512 dims, 10 classes.
#define NROWS   131072
#define DIMS    512
#define NC      10
#define SEG_BLOCKS 1024       // 128 rows per block, 256 threads (4 waves)
#define SUMSTRIDE 5120        // 10*512 floats per partial copy

typedef __attribute__((ext_vector_type(8))) short short8;   // 8 bf16 in 4 VGPRs
typedef __attribute__((ext_vector_type(4))) float floatx4;

// ---- helpers -------------------------------------------------------------

static __device__ __forceinline__ unsigned int pk2(float lo, float hi) {
    // pack two fp32 -> two bf16 (truncation; abs error 4.0 vs threshold 13.5)
    return (__float_as_uint(hi) & 0xFFFF0000u) | (__float_as_uint(lo) >> 16);
}

static __device__ __forceinline__ short8 pack8(const float4 a, const float4 b) {
    union { unsigned int u[4]; short8 v; } r;
    r.u[0] = pk2(a.x, a.y);
    r.u[1] = pk2(a.z, a.w);
    r.u[2] = pk2(b.x, b.y);
    r.u[3] = pk2(b.z, b.w);
    return r.v;
}

// ---- kernel 1: per-block segment sums + fp32 row norms -------------------
// 1024 blocks x 256 threads. half = tid>>7, dt = tid&127. Thread covers dims
// [4dt,4dt+4) of rows rows0 + 2i + half, i<64. Register accumulators with
// ALL-STATIC indexing (any dynamic index over a0..a9 demotes to scratch).
// Depth-3 pipeline: 2 outstanding loads/wave.
// Round-2: E16 copy REMOVED (all k_seg blocks are co-resident, so the L3
// residue is striped per-chunk; a bf16 copy buys nothing over re-reading
// fp32 from L3 and costs 128 MB of writes). Norms kept: exact fp32 row
// norms ride free on k_seg's issue slack and delete VALU from k_main.

__global__ __launch_bounds__(256) void k_seg(const float* __restrict__ E,
                                             const int* __restrict__ L,
                                             float* __restrict__ part,
                                             int* __restrict__ counts,
                                             float* __restrict__ norms) {
    __shared__ float4 R[NC * 128];   // 20 KB merge buffer
    __shared__ float ns[4 * 64];     // per-wave, per-iter norm partials
    __shared__ int lc[16];
    const int tid  = threadIdx.x;
    const int half = tid >> 7;
    const int dt   = tid & 127;
    const int wid  = tid >> 6;
    const int lane = tid & 63;
    if (tid < 16) lc[tid] = 0;
    __syncthreads();

    const int rows0 = blockIdx.x * 128;
    const float4* Ev = (const float4*)E;

    float4 z = {0.f, 0.f, 0.f, 0.f};
    float4 a0=z,a1=z,a2=z,a3=z,a4=z,a5=z,a6=z,a7=z,a8=z,a9=z;

    int idx = (rows0 + half) * 128 + dt;       // row stride 2 => +256 float4
    float4 v0 = Ev[idx];
    float4 v1 = Ev[idx + 256];
    int l0 = L[rows0 + half];
    int l1 = L[rows0 + 2 + half];

    for (int i = 0; i < 64; ++i) {
        float4 v2; int l2;
        const bool pf = (i < 62);
        if (pf) {                               // prefetch 2 rows ahead
            v2 = Ev[idx + 512];
            l2 = L[rows0 + 2 * i + 4 + half];
        }
        if (dt == 0) atomicAdd(&lc[l0], 1);     // 2 lanes x 64 iters = 128 rows

        // exact fp32 norm partial for this row slice; wave-reduce (dt 0..63
        // in this wave); cross-wave halves combined after the barrier.
        float p = v0.x*v0.x + v0.y*v0.y + v0.z*v0.z + v0.w*v0.w;
        p += __shfl_xor(p, 1);  p += __shfl_xor(p, 2);
        p += __shfl_xor(p, 4);  p += __shfl_xor(p, 8);
        p += __shfl_xor(p, 16); p += __shfl_xor(p, 32);
        if (lane == 0) ns[wid * 64 + i] = p;

        switch (l0) {                           // wave-uniform -> scalar branch
            case 0: a0.x+=v0.x; a0.y+=v0.y; a0.z+=v0.z; a0.w+=v0.w; break;
            case 1: a1.x+=v0.x; a1.y+=v0.y; a1.z+=v0.z; a1.w+=v0.w; break;
            case 2: a2.x+=v0.x; a2.y+=v0.y; a2.z+=v0.z; a2.w+=v0.w; break;
            case 3: a3.x+=v0.x; a3.y+=v0.y; a3.z+=v0.z; a3.w+=v0.w; break;
            case 4: a4.x+=v0.x; a4.y+=v0.y; a4.z+=v0.z; a4.w+=v0.w; break;
            case 5: a5.x+=v0.x; a5.y+=v0.y; a5.z+=v0.z; a5.w+=v0.w; break;
            case 6: a6.x+=v0.x; a6.y+=v0.y; a6.z+=v0.z; a6.w+=v0.w; break;
            case 7: a7.x+=v0.x; a7.y+=v0.y; a7.z+=v0.z; a7.w+=v0.w; break;
            case 8: a8.x+=v0.x; a8.y+=v0.y; a8.z+=v0.z; a8.w+=v0.w; break;
            default: a9.x+=v0.x; a9.y+=v0.y; a9.z+=v0.z; a9.w+=v0.w; break;
        }
        v0 = v1; l0 = l1;
        if (pf) { v1 = v2; l1 = l2; }
        idx += 256;
    }

    // static LDS merge: half-1 stores, half-0 adds + writes partials
    if (half) {
        R[0*128+dt]=a0; R[1*128+dt]=a1; R[2*128+dt]=a2; R[3*128+dt]=a3;
        R[4*128+dt]=a4; R[5*128+dt]=a5; R[6*128+dt]=a6; R[7*128+dt]=a7;
        R[8*128+dt]=a8; R[9*128+dt]=a9;
    }
    __syncthreads();
    if (!half) {
        float4* dst = (float4*)(part + (size_t)blockIdx.x * SUMSTRIDE);
        float4 t;
#define MERGE_ST(c, ac)                                                       \
        t = R[(c)*128 + dt];                                                  \
        t.x += ac.x; t.y += ac.y; t.z += ac.z; t.w += ac.w;                   \
        dst[(c)*128 + dt] = t;
        MERGE_ST(0,a0) MERGE_ST(1,a1) MERGE_ST(2,a2) MERGE_ST(3,a3)
        MERGE_ST(4,a4) MERGE_ST(5,a5) MERGE_ST(6,a6) MERGE_ST(7,a7)
        MERGE_ST(8,a8) MERGE_ST(9,a9)
#undef MERGE_ST
    }
    // row j (=tid) = 2i+h -> combine the two waves of that half.
    if (tid < 128) {
        const int i2 = tid >> 1, h2 = tid & 1;
        norms[rows0 + tid] = ns[(2*h2)*64 + i2] + ns[(2*h2+1)*64 + i2];
    }
    if (tid < 16) counts[blockIdx.x * 16 + tid] = lc[tid];
}

// ---- kernel 2 (fused, replaces k_red + k_pp): part -> p2 directly --------
// 64 blocks x 256 threads. Blocks 0..39: element range [b*128, b*128+128) of
// the 5120-element [c][dim] sum; class c = b>>2 is block-uniform. Each block
// reduces its class count from counts[1024][16], reduces 1024 partial
// copies, writes p2 = 2*sum/cnt. Blocks 40..63 zero-pad classes 10..15.
// pn (||p||^2) moved into k_main's fragment-build loop (it touches every
// fp32 p2 element there anyway). part is freshly written by k_seg -> L3-hot.

__global__ __launch_bounds__(256) void k_red2(const float* __restrict__ part,
                                              const int* __restrict__ counts,
                                              float* __restrict__ p2,
                                              float* __restrict__ out) {
    __shared__ float m[128];
    __shared__ int cs[256];
    const int t = threadIdx.x;
    const int b = blockIdx.x;
    const int col = t & 127, kh = t >> 7;

    if (b >= 40) {                               // zero-pad classes 10..15
        if (kh == 0) p2[5120 + (b - 40) * 128 + col] = 0.f;
        return;
    }
    if (b == 0 && t == 0) out[0] = 0.f;          // loss accumulator (pre-k_main)

    // class count for this block's (uniform) class
    const int c = b >> 2;
    {
        int s = 0;
        for (int j = t; j < 1024; j += 256) s += counts[j * 16 + c];
        cs[t] = s;
    }
    __syncthreads();
    if (t < 64) cs[t] += cs[t + 64] + cs[t + 128] + cs[t + 192];
    __syncthreads();
    if (t < 8)  cs[t] += cs[t + 8] + cs[t + 16] + cs[t + 24] + cs[t + 32]
                       + cs[t + 40] + cs[t + 48] + cs[t + 56];
    __syncthreads();
    if (t == 0) cs[0] += cs[1] + cs[2] + cs[3] + cs[4] + cs[5] + cs[6] + cs[7];
    __syncthreads();
    const float inv = 1.f / (float)cs[0];

    // reduce 1024 copies: kh-half covers 512 copies, 4-way ILP
    const float* base = part + (size_t)(kh * 512) * SUMSTRIDE + b * 128 + col;
    float s0=0.f, s1=0.f, s2=0.f, s3=0.f;
    for (int j = 0; j < 512; j += 4) {
        s0 += base[(size_t)(j + 0) * SUMSTRIDE];
        s1 += base[(size_t)(j + 1) * SUMSTRIDE];
        s2 += base[(size_t)(j + 2) * SUMSTRIDE];
        s3 += base[(size_t)(j + 3) * SUMSTRIDE];
    }
    float s = (s0 + s1) + (s2 + s3);
    if (kh) m[col] = s;
    __syncthreads();
    if (!kh) p2[b * 128 + col] = 2.f * (s + m[col]) * inv;
}

// ---- kernel 3: distances + logits + log-softmax + loss -------------------
// One wave per 16-row tile; MFMA 16x16x32 bf16 for the 2*e.p cross term.
// Round-2: back to fp32 E loads (pack8 on the fly -> MFMA inputs identical
// to all prior rounds); reverse tile order exploits the striped L3 residue
// from k_seg. Row norms come precomputed from k_seg (exact fp32); per-class
// ||p||^2 computed in the fragment-build preamble (replaces k_pp's pn).
// A-frag: lane holds row (lane&15), k = (lane>>4)*8 + j   [verified layout]
// C/D:    lane holds col (lane&15), rows (lane>>4)*4 + reg [verified layout]

__global__ __launch_bounds__(256, 2) void k_main(const float* __restrict__ E,
                                                 const float* __restrict__ norms,
                                                 const int* __restrict__ L,
                                                 const float* __restrict__ p2,
                                                 float* __restrict__ out) {
    const int tid  = threadIdx.x;
    const int wid  = tid >> 6, lane = tid & 63;
    const int c16  = lane & 15, quad = lane >> 4;

    // B fragments (prototypes as bf16) + ||p||^2, built once per wave.
    // Lane covers dims kt*32 + quad*8 .. +7 for kt=0..15 -> the 4 quads
    // cover all 512 dims; reduce ss over quad (shfl 16,32). Exact fp32.
    short8 bf[16];
    float ss = 0.f;
    const float4* P = (const float4*)p2;
#pragma unroll
    for (int kt = 0; kt < 16; ++kt) {
        float4 a = P[c16 * 128 + kt * 8 + quad * 2];
        float4 b = P[c16 * 128 + kt * 8 + quad * 2 + 1];
        ss += a.x*a.x + a.y*a.y + a.z*a.z + a.w*a.w
            + b.x*b.x + b.y*b.y + b.z*b.z + b.w*b.w;
        bf[kt] = pack8(a, b);
    }
    ss += __shfl_xor(ss, 16);
    ss += __shfl_xor(ss, 32);
    const float pnc = 0.25f * ss;               // p2 = 2p -> ||p||^2 = ss/4

    float lossp = 0.f;
    const int gw = blockIdx.x * 4 + wid;            // 0..4095
    for (int t = gw; t < 8192; t += 4096) {
        const int tile  = 8191 - t;                 // reverse order: L3-friendly
        const int rbase = tile * 16;
        const float4* A = (const float4*)(E + (size_t)(rbase + c16) * DIMS);
        const float nmine = norms[rbase + c16];     // lane j: norm of row (j&15)

        floatx4 acc = {0.f, 0.f, 0.f, 0.f};
#pragma unroll
        for (int kt = 0; kt < 16; ++kt) {
            float4 a = A[kt * 8 + quad * 2];
            float4 b = A[kt * 8 + quad * 2 + 1];
            acc = __builtin_amdgcn_mfma_f32_16x16x32_bf16(pack8(a, b), bf[kt],
                                                          acc, 0, 0, 0);
        }

#pragma unroll
        for (int i = 0; i < 4; ++i) {
            const int row = rbase + quad * 4 + i;
            const float nr = __shfl(nmine, quad * 4 + i); // norm of row
            float lg = acc[i] - nr - pnc;                  // = 2e.p - ||e||^2 - ||p||^2 = -d2
            lg = fminf(lg, 0.f);                           // reference clamps d2 >= 0
            float ml = (c16 < NC) ? lg : -3.0e38f;
            ml = fmaxf(ml, __shfl_xor(ml, 1));
            ml = fmaxf(ml, __shfl_xor(ml, 2));
            ml = fmaxf(ml, __shfl_xor(ml, 4));
            ml = fmaxf(ml, __shfl_xor(ml, 8));
            float ex = (c16 < NC) ? __expf(lg - ml) : 0.f;
            ex += __shfl_xor(ex, 1);
            ex += __shfl_xor(ex, 2);
            ex += __shfl_xor(ex, 4);
            ex += __shfl_xor(ex, 8);
            const float lse = ml + __logf(ex);
            if (c16 < NC) out[1 + row * NC + c16] = lg;
            const int lab = L[row];
            if (c16 == lab) lossp += lse - lg;
        }
    }

    lossp += __shfl_xor(lossp, 1);  lossp += __shfl_xor(lossp, 2);
    lossp += __shfl_xor(lossp, 4);  lossp += __shfl_xor(lossp, 8);
    lossp += __shfl_xor(lossp, 16); lossp += __shfl_xor(lossp, 32);
    __shared__ float ls[4];
    if (lane == 0) ls[wid] = lossp;
    __syncthreads();
    if (tid == 0)
        atomicAdd(out, (ls[0] + ls[1] + ls[2] + ls[3]) * (1.0f / (float)NROWS));
}

// ---- launch --------------------------------------------------------------

extern "C" void kernel_launch(void* const* d_in, const int* in_sizes, int n_in,
                              void* d_out, int out_size, void* d_ws, size_t ws_size,
                              hipStream_t stream) {
    const float* E = (const float*)d_in[0];
    const int*   L = (const int*)d_in[1];
    float* out = (float*)d_out;
    char* ws = (char*)d_ws;

    // ws layout (bytes):
    //   part   1024*5120*4 = 20971520   @ 0
    //   counts 1024*16*4   =    65536   @ 20971520
    //   p2     16*512*4    =    32768   @ 21037056
    //   norms  131072*4    =   524288   @ 21069824
    float* part   = (float*)ws;
    int*   counts = (int*)  (ws + 20971520);
    float* p2     = (float*)(ws + 21037056);
    float* norms  = (float*)(ws + 21069824);

    k_seg <<<SEG_BLOCKS, 256, 0, stream>>>(E, L, part, counts, norms);
    k_red2<<<64,         256, 0, stream>>>(part, counts, p2, out);
    k_main<<<1024,       256, 0, stream>>>(E, norms, L, p2, out);
}

// Round 3
// 430.270 us; speedup vs baseline: 1.1614x; 1.1614x over previous
//
#include <hip/hip_runtime.h>

// Problem constants (fixed by the reference): 131072 rows x 512 dims, 10 classes.
#define NROWS   131072
#define DIMS    512
#define NC      10
#define SEG_BLOCKS 1024       // 128 rows per block, 256 threads (4 waves)
#define SUMSTRIDE 5120        // 10*512 floats per partial copy

typedef __attribute__((ext_vector_type(8))) short short8;   // 8 bf16 in 4 VGPRs
typedef __attribute__((ext_vector_type(4))) float floatx4;

// ---- helpers -------------------------------------------------------------

static __device__ __forceinline__ unsigned int pk2(float lo, float hi) {
    // pack two fp32 -> two bf16 (truncation; abs error 4.0 vs threshold 13.5)
    return (__float_as_uint(hi) & 0xFFFF0000u) | (__float_as_uint(lo) >> 16);
}

static __device__ __forceinline__ short8 pack8(const float4 a, const float4 b) {
    union { unsigned int u[4]; short8 v; } r;
    r.u[0] = pk2(a.x, a.y);
    r.u[1] = pk2(a.z, a.w);
    r.u[2] = pk2(b.x, b.y);
    r.u[3] = pk2(b.z, b.w);
    return r.v;
}

// ---- kernel 1: per-block segment sums + bf16 copy + fp32 row norms -------
// 1024 blocks x 256 threads. half = tid>>7, dt = tid&127. Thread covers dims
// [4dt,4dt+4) of rows rows0 + 2i + half, i<64. Register accumulators with
// ALL-STATIC indexing (any dynamic index over a0..a9 demotes to scratch).
// Depth-3 pipeline: 2 outstanding loads/wave.
// Round-3 change: fp32 E reads are NON-TEMPORAL (nt / evict-first). Round 1
// showed the E16 copy is a wash when the 268 MB fp32 stream thrashes L3 and
// evicts the freshly-written E16 lines. With nt reads, L3 after k_seg holds
// the 134 MB E16 copy -> k_main reads hit L3 instead of HBM.

__global__ __launch_bounds__(256) void k_seg(const float* __restrict__ E,
                                             const int* __restrict__ L,
                                             float* __restrict__ part,
                                             int* __restrict__ counts,
                                             uint2* __restrict__ E16,
                                             float* __restrict__ norms) {
    __shared__ float4 R[NC * 128];   // 20 KB merge buffer
    __shared__ float ns[4 * 64];     // per-wave, per-iter norm partials
    __shared__ int lc[16];
    const int tid  = threadIdx.x;
    const int half = tid >> 7;
    const int dt   = tid & 127;
    const int wid  = tid >> 6;
    const int lane = tid & 63;
    if (tid < 16) lc[tid] = 0;
    __syncthreads();

    const int rows0 = blockIdx.x * 128;
    const floatx4* Ev = (const floatx4*)E;

    float4 z = {0.f, 0.f, 0.f, 0.f};
    float4 a0=z,a1=z,a2=z,a3=z,a4=z,a5=z,a6=z,a7=z,a8=z,a9=z;

    int idx = (rows0 + half) * 128 + dt;       // row stride 2 => +256 float4
    floatx4 v0 = __builtin_nontemporal_load(&Ev[idx]);
    floatx4 v1 = __builtin_nontemporal_load(&Ev[idx + 256]);
    int l0 = L[rows0 + half];
    int l1 = L[rows0 + 2 + half];

    for (int i = 0; i < 64; ++i) {
        floatx4 v2; int l2;
        const bool pf = (i < 62);
        if (pf) {                               // prefetch 2 rows ahead
            v2 = __builtin_nontemporal_load(&Ev[idx + 512]);
            l2 = L[rows0 + 2 * i + 4 + half];
        }
        if (dt == 0) atomicAdd(&lc[l0], 1);     // 2 lanes x 64 iters = 128 rows

        // bf16 copy: E16 uint2-index == idx (same row*128+dt layout), 8B/lane.
        // Regular (temporal) store: we WANT these lines resident in L3.
        uint2 uu;
        uu.x = pk2(v0.x, v0.y);
        uu.y = pk2(v0.z, v0.w);
        E16[idx] = uu;

        // exact fp32 norm partial for this row slice; wave-reduce (dt 0..63
        // in this wave); cross-wave halves combined after the barrier.
        float p = v0.x*v0.x + v0.y*v0.y + v0.z*v0.z + v0.w*v0.w;
        p += __shfl_xor(p, 1);  p += __shfl_xor(p, 2);
        p += __shfl_xor(p, 4);  p += __shfl_xor(p, 8);
        p += __shfl_xor(p, 16); p += __shfl_xor(p, 32);
        if (lane == 0) ns[wid * 64 + i] = p;

        switch (l0) {                           // wave-uniform -> scalar branch
            case 0: a0.x+=v0.x; a0.y+=v0.y; a0.z+=v0.z; a0.w+=v0.w; break;
            case 1: a1.x+=v0.x; a1.y+=v0.y; a1.z+=v0.z; a1.w+=v0.w; break;
            case 2: a2.x+=v0.x; a2.y+=v0.y; a2.z+=v0.z; a2.w+=v0.w; break;
            case 3: a3.x+=v0.x; a3.y+=v0.y; a3.z+=v0.z; a3.w+=v0.w; break;
            case 4: a4.x+=v0.x; a4.y+=v0.y; a4.z+=v0.z; a4.w+=v0.w; break;
            case 5: a5.x+=v0.x; a5.y+=v0.y; a5.z+=v0.z; a5.w+=v0.w; break;
            case 6: a6.x+=v0.x; a6.y+=v0.y; a6.z+=v0.z; a6.w+=v0.w; break;
            case 7: a7.x+=v0.x; a7.y+=v0.y; a7.z+=v0.z; a7.w+=v0.w; break;
            case 8: a8.x+=v0.x; a8.y+=v0.y; a8.z+=v0.z; a8.w+=v0.w; break;
            default: a9.x+=v0.x; a9.y+=v0.y; a9.z+=v0.z; a9.w+=v0.w; break;
        }
        v0 = v1; l0 = l1;
        if (pf) { v1 = v2; l1 = l2; }
        idx += 256;
    }

    // static LDS merge: half-1 stores, half-0 adds + writes partials
    if (half) {
        R[0*128+dt]=a0; R[1*128+dt]=a1; R[2*128+dt]=a2; R[3*128+dt]=a3;
        R[4*128+dt]=a4; R[5*128+dt]=a5; R[6*128+dt]=a6; R[7*128+dt]=a7;
        R[8*128+dt]=a8; R[9*128+dt]=a9;
    }
    __syncthreads();
    if (!half) {
        float4* dst = (float4*)(part + (size_t)blockIdx.x * SUMSTRIDE);
        float4 t;
#define MERGE_ST(c, ac)                                                       \
        t = R[(c)*128 + dt];                                                  \
        t.x += ac.x; t.y += ac.y; t.z += ac.z; t.w += ac.w;                   \
        dst[(c)*128 + dt] = t;
        MERGE_ST(0,a0) MERGE_ST(1,a1) MERGE_ST(2,a2) MERGE_ST(3,a3)
        MERGE_ST(4,a4) MERGE_ST(5,a5) MERGE_ST(6,a6) MERGE_ST(7,a7)
        MERGE_ST(8,a8) MERGE_ST(9,a9)
#undef MERGE_ST
    }
    // row j (=tid) = 2i+h -> combine the two waves of that half.
    if (tid < 128) {
        const int i2 = tid >> 1, h2 = tid & 1;
        norms[rows0 + tid] = ns[(2*h2)*64 + i2] + ns[(2*h2+1)*64 + i2];
    }
    if (tid < 16) counts[blockIdx.x * 16 + tid] = lc[tid];
}

// ---- kernel 2: reduce 1024 partial copies -> 8 partial copies ------------
// 320 blocks = 40 col-chunks x 8 copy-chunks; each block: 128 cols x 128
// copies. (Round-2 lesson: do NOT shrink this below ~300 blocks — a 40-block
// fused variant was latency-bound on 40 CUs and cost +47 us.)

__global__ __launch_bounds__(256) void k_red(const float* __restrict__ part,
                                             float* __restrict__ psum8) {
    __shared__ float m[128];
    const int t   = threadIdx.x;
    const int col = t & 127, kh = t >> 7;
    const int cc  = blockIdx.x % 40;
    const int kc  = blockIdx.x / 40;
    const int e   = cc * 128 + col;

    const float* base = part + (size_t)(kc * 128 + kh * 64) * SUMSTRIDE + e;
    float s0=0.f, s1=0.f, s2=0.f, s3=0.f;
    for (int j = 0; j < 64; j += 4) {        // 4-way ILP over 64 copies
        s0 += base[(size_t)(j + 0) * SUMSTRIDE];
        s1 += base[(size_t)(j + 1) * SUMSTRIDE];
        s2 += base[(size_t)(j + 2) * SUMSTRIDE];
        s3 += base[(size_t)(j + 3) * SUMSTRIDE];
    }
    float s = (s0 + s1) + (s2 + s3);
    if (kh) m[col] = s;
    __syncthreads();
    if (!kh) psum8[kc * SUMSTRIDE + e] = s + m[col];
}

// ---- kernel 3: prototypes + ||p||^2 + zero loss (single block) -----------
// part/psum8 element order is [c][dim] (from k_seg's R layout).

__global__ __launch_bounds__(512) void k_pp(const float* __restrict__ psum8,
                                            const int* __restrict__ counts,
                                            float* __restrict__ p2,
                                            float* __restrict__ pn,
                                            float* __restrict__ out) {
    __shared__ float P[16 * DIMS];   // 32 KB
    __shared__ int tmp[512];
    __shared__ int cnt[16];
    const int t = threadIdx.x;

    // counts: 1024 copies x 16 -> cnt[16]
    {
        const int c0 = t & 15, chunk = t >> 4;   // 32 chunks x 32 copies
        int s = 0;
        for (int j = 0; j < 32; ++j) s += counts[(chunk * 32 + j) * 16 + c0];
        tmp[t] = s;
    }
    __syncthreads();
    if (t < 16) {
        int n = 0;
        for (int ch = 0; ch < 32; ++ch) n += tmp[ch * 16 + t];
        cnt[t] = n;
    }
    if (t == 0) out[0] = 0.f;                    // loss accumulator
    __syncthreads();

    for (int e = t; e < 16 * DIMS; e += 512) {   // p2 = 2*prototype, zero-padded
        const int c = e >> 9;
        float val = 0.f;
        if (c < NC) {
            float s = 0.f;
#pragma unroll
            for (int j = 0; j < 8; ++j) s += psum8[j * SUMSTRIDE + e];
            val = 2.f * s / (float)cnt[c];
        }
        p2[e] = val;
        P[e] = val;
    }
    __syncthreads();

    const int w = t >> 6, lane = t & 63;
    const float4* Pv = (const float4*)P;
    for (int sdx = 0; sdx < 2; ++sdx) {
        const int c = w + sdx * 8;               // covers 0..15
        float4 a = Pv[c * 128 + lane * 2];
        float4 b = Pv[c * 128 + lane * 2 + 1];
        float ss = a.x*a.x + a.y*a.y + a.z*a.z + a.w*a.w
                 + b.x*b.x + b.y*b.y + b.z*b.z + b.w*b.w;
        ss += __shfl_xor(ss, 1);  ss += __shfl_xor(ss, 2);
        ss += __shfl_xor(ss, 4);  ss += __shfl_xor(ss, 8);
        ss += __shfl_xor(ss, 16); ss += __shfl_xor(ss, 32);
        if (lane == 0) pn[c] = 0.25f * ss;       // p2 = 2p -> /4
    }
}

// ---- kernel 4: distances + logits + log-softmax + loss -------------------
// One wave per 16-row tile; MFMA 16x16x32 bf16 for the 2*e.p cross term.
// A-operand from the bf16 copy (should now be L3-resident thanks to k_seg's
// nt reads); exact fp32 row norms from k_seg. Logit stores non-temporal
// (write-once, 5 MB — keep them out of L3).
// A-frag: lane holds row (lane&15), k = (lane>>4)*8 + j   [verified layout]
// C/D:    lane holds col (lane&15), rows (lane>>4)*4 + reg [verified layout]

__global__ __launch_bounds__(256, 2) void k_main(const ushort* __restrict__ E16,
                                                 const float* __restrict__ norms,
                                                 const int* __restrict__ L,
                                                 const float* __restrict__ p2,
                                                 const float* __restrict__ pn,
                                                 float* __restrict__ out) {
    const int tid  = threadIdx.x;
    const int wid  = tid >> 6, lane = tid & 63;
    const int c16  = lane & 15, quad = lane >> 4;

    // B fragments (prototypes as bf16), built once per wave: 64 VGPRs
    short8 bf[16];
    const float4* P = (const float4*)p2;
#pragma unroll
    for (int kt = 0; kt < 16; ++kt) {
        float4 a = P[c16 * 128 + kt * 8 + quad * 2];
        float4 b = P[c16 * 128 + kt * 8 + quad * 2 + 1];
        bf[kt] = pack8(a, b);
    }
    const float pnc = pn[c16];

    float lossp = 0.f;
    const int gw = blockIdx.x * 4 + wid;            // 0..4095
    for (int t = gw; t < 8192; t += 4096) {
        const int tile  = 8191 - t;                 // reverse order: L3-friendly
        const int rbase = tile * 16;
        // row stride = 512 bf16 = 32 short8 units; frag kt at dims kt*32+quad*8
        const short8* A = (const short8*)(E16 + (size_t)(rbase + c16) * DIMS);
        const float nmine = norms[rbase + c16];     // lane j: norm of row (j&15)

        floatx4 acc = {0.f, 0.f, 0.f, 0.f};
#pragma unroll
        for (int kt = 0; kt < 16; ++kt) {
            acc = __builtin_amdgcn_mfma_f32_16x16x32_bf16(A[kt * 4 + quad],
                                                          bf[kt], acc, 0, 0, 0);
        }

#pragma unroll
        for (int i = 0; i < 4; ++i) {
            const int row = rbase + quad * 4 + i;
            const float nr = __shfl(nmine, quad * 4 + i); // norm of row
            float lg = acc[i] - nr - pnc;                  // = 2e.p - ||e||^2 - ||p||^2 = -d2
            lg = fminf(lg, 0.f);                           // reference clamps d2 >= 0
            float ml = (c16 < NC) ? lg : -3.0e38f;
            ml = fmaxf(ml, __shfl_xor(ml, 1));
            ml = fmaxf(ml, __shfl_xor(ml, 2));
            ml = fmaxf(ml, __shfl_xor(ml, 4));
            ml = fmaxf(ml, __shfl_xor(ml, 8));
            float ex = (c16 < NC) ? __expf(lg - ml) : 0.f;
            ex += __shfl_xor(ex, 1);
            ex += __shfl_xor(ex, 2);
            ex += __shfl_xor(ex, 4);
            ex += __shfl_xor(ex, 8);
            const float lse = ml + __logf(ex);
            if (c16 < NC)
                __builtin_nontemporal_store(lg, &out[1 + row * NC + c16]);
            const int lab = L[row];
            if (c16 == lab) lossp += lse - lg;
        }
    }

    lossp += __shfl_xor(lossp, 1);  lossp += __shfl_xor(lossp, 2);
    lossp += __shfl_xor(lossp, 4);  lossp += __shfl_xor(lossp, 8);
    lossp += __shfl_xor(lossp, 16); lossp += __shfl_xor(lossp, 32);
    __shared__ float ls[4];
    if (lane == 0) ls[wid] = lossp;
    __syncthreads();
    if (tid == 0)
        atomicAdd(out, (ls[0] + ls[1] + ls[2] + ls[3]) * (1.0f / (float)NROWS));
}

// ---- launch --------------------------------------------------------------

extern "C" void kernel_launch(void* const* d_in, const int* in_sizes, int n_in,
                              void* d_out, int out_size, void* d_ws, size_t ws_size,
                              hipStream_t stream) {
    const float* E = (const float*)d_in[0];
    const int*   L = (const int*)d_in[1];
    float* out = (float*)d_out;
    char* ws = (char*)d_ws;

    // ws layout (bytes):
    //   part   1024*5120*4 = 20971520   @ 0
    //   psum8     8*5120*4 =   163840   @ 20971520
    //   counts 1024*16*4   =    65536   @ 21135360
    //   p2     16*512*4    =    32768   @ 21200896
    //   pn     16*4        =       64   @ 21233664
    //   norms  131072*4    =   524288   @ 21233728
    //   E16    131072*512*2=134217728   @ 21758016  (16B aligned)
    float* part   = (float*)ws;
    float* psum8  = (float*)(ws + 20971520);
    int*   counts = (int*)  (ws + 21135360);
    float* p2     = (float*)(ws + 21200896);
    float* pn     = (float*)(ws + 21233664);
    float* norms  = (float*)(ws + 21233728);
    uint2* E16    = (uint2*)(ws + 21758016);

    k_seg <<<SEG_BLOCKS, 256, 0, stream>>>(E, L, part, counts, E16, norms);
    k_red <<<320,        256, 0, stream>>>(part, psum8);
    k_pp  <<<1,          512, 0, stream>>>(psum8, counts, p2, pn, out);
    k_main<<<1024,       256, 0, stream>>>((const ushort*)E16, norms, L, p2, pn, out);
}

// Round 6
// 428.443 us; speedup vs baseline: 1.1663x; 1.0043x over previous
//
#include <hip/hip_runtime.h>

// Problem constants (fixed by the reference): 131072 rows x 512 dims, 10 classes.
#define NROWS   131072
#define DIMS    512
#define NC      10
#define SEG_BLOCKS 1024       // 128 rows per block, 256 threads (4 waves)
#define SUMSTRIDE 5120        // 10*512 floats per partial copy

typedef __attribute__((ext_vector_type(8))) short short8;   // 8 bf16 in 4 VGPRs
typedef __attribute__((ext_vector_type(4))) float floatx4;

// ---- helpers -------------------------------------------------------------

static __device__ __forceinline__ unsigned int pk2(float lo, float hi) {
    // pack two fp32 -> two bf16 (truncation; abs error 4.0 vs threshold 13.5)
    return (__float_as_uint(hi) & 0xFFFF0000u) | (__float_as_uint(lo) >> 16);
}

static __device__ __forceinline__ short8 pack8(const float4 a, const float4 b) {
    union { unsigned int u[4]; short8 v; } r;
    r.u[0] = pk2(a.x, a.y);
    r.u[1] = pk2(a.z, a.w);
    r.u[2] = pk2(b.x, b.y);
    r.u[3] = pk2(b.z, b.w);
    return r.v;
}

// ---- kernel 1: per-block segment sums + bf16 copy + fp32 row norms -------
// 1024 blocks x 256 threads. half = tid>>7, dt = tid&127. Thread covers dims
// [4dt,4dt+4) of rows rows0 + 2i + half, i<64. Register accumulators with
// ALL-STATIC indexing (any dynamic index over a0..a9 demotes to scratch).
// Depth-3 pipeline: 2 outstanding loads/wave.
// fp32 E reads are NON-TEMPORAL (evict-first): keeps the 268 MB stream out
// of L3 so the freshly-written 134 MB E16 copy stays resident for k_main.
// (Verified round 3: 453 -> 430 us; without nt the copy is a wash.)
// NOTE (rounds 4/5 lesson): no cross-kernel atomic counters anywhere — a
// last-block-election variant failed the container twice; every kernel here
// is self-contained and dispatch-replay-safe.

__global__ __launch_bounds__(256) void k_seg(const float* __restrict__ E,
                                             const int* __restrict__ L,
                                             float* __restrict__ part,
                                             int* __restrict__ counts,
                                             uint2* __restrict__ E16,
                                             float* __restrict__ norms) {
    __shared__ float4 R[NC * 128];   // 20 KB merge buffer
    __shared__ float ns[4 * 64];     // per-wave, per-iter norm partials
    __shared__ int lc[16];
    const int tid  = threadIdx.x;
    const int half = tid >> 7;
    const int dt   = tid & 127;
    const int wid  = tid >> 6;
    const int lane = tid & 63;
    if (tid < 16) lc[tid] = 0;
    __syncthreads();

    const int rows0 = blockIdx.x * 128;
    const floatx4* Ev = (const floatx4*)E;

    float4 z = {0.f, 0.f, 0.f, 0.f};
    float4 a0=z,a1=z,a2=z,a3=z,a4=z,a5=z,a6=z,a7=z,a8=z,a9=z;

    int idx = (rows0 + half) * 128 + dt;       // row stride 2 => +256 float4
    floatx4 v0 = __builtin_nontemporal_load(&Ev[idx]);
    floatx4 v1 = __builtin_nontemporal_load(&Ev[idx + 256]);
    int l0 = L[rows0 + half];
    int l1 = L[rows0 + 2 + half];

    for (int i = 0; i < 64; ++i) {
        floatx4 v2; int l2;
        const bool pf = (i < 62);
        if (pf) {                               // prefetch 2 rows ahead
            v2 = __builtin_nontemporal_load(&Ev[idx + 512]);
            l2 = L[rows0 + 2 * i + 4 + half];
        }
        if (dt == 0) atomicAdd(&lc[l0], 1);     // 2 lanes x 64 iters = 128 rows

        // bf16 copy: E16 uint2-index == idx (same row*128+dt layout), 8B/lane.
        // Regular (temporal) store: we WANT these lines resident in L3.
        uint2 uu;
        uu.x = pk2(v0.x, v0.y);
        uu.y = pk2(v0.z, v0.w);
        E16[idx] = uu;

        // exact fp32 norm partial for this row slice; wave-reduce (dt 0..63
        // in this wave); cross-wave halves combined after the barrier.
        float p = v0.x*v0.x + v0.y*v0.y + v0.z*v0.z + v0.w*v0.w;
        p += __shfl_xor(p, 1);  p += __shfl_xor(p, 2);
        p += __shfl_xor(p, 4);  p += __shfl_xor(p, 8);
        p += __shfl_xor(p, 16); p += __shfl_xor(p, 32);
        if (lane == 0) ns[wid * 64 + i] = p;

        switch (l0) {                           // wave-uniform -> scalar branch
            case 0: a0.x+=v0.x; a0.y+=v0.y; a0.z+=v0.z; a0.w+=v0.w; break;
            case 1: a1.x+=v0.x; a1.y+=v0.y; a1.z+=v0.z; a1.w+=v0.w; break;
            case 2: a2.x+=v0.x; a2.y+=v0.y; a2.z+=v0.z; a2.w+=v0.w; break;
            case 3: a3.x+=v0.x; a3.y+=v0.y; a3.z+=v0.z; a3.w+=v0.w; break;
            case 4: a4.x+=v0.x; a4.y+=v0.y; a4.z+=v0.z; a4.w+=v0.w; break;
            case 5: a5.x+=v0.x; a5.y+=v0.y; a5.z+=v0.z; a5.w+=v0.w; break;
            case 6: a6.x+=v0.x; a6.y+=v0.y; a6.z+=v0.z; a6.w+=v0.w; break;
            case 7: a7.x+=v0.x; a7.y+=v0.y; a7.z+=v0.z; a7.w+=v0.w; break;
            case 8: a8.x+=v0.x; a8.y+=v0.y; a8.z+=v0.z; a8.w+=v0.w; break;
            default: a9.x+=v0.x; a9.y+=v0.y; a9.z+=v0.z; a9.w+=v0.w; break;
        }
        v0 = v1; l0 = l1;
        if (pf) { v1 = v2; l1 = l2; }
        idx += 256;
    }

    // static LDS merge: half-1 stores, half-0 adds + writes partials
    if (half) {
        R[0*128+dt]=a0; R[1*128+dt]=a1; R[2*128+dt]=a2; R[3*128+dt]=a3;
        R[4*128+dt]=a4; R[5*128+dt]=a5; R[6*128+dt]=a6; R[7*128+dt]=a7;
        R[8*128+dt]=a8; R[9*128+dt]=a9;
    }
    __syncthreads();
    if (!half) {
        float4* dst = (float4*)(part + (size_t)blockIdx.x * SUMSTRIDE);
        float4 t;
#define MERGE_ST(c, ac)                                                       \
        t = R[(c)*128 + dt];                                                  \
        t.x += ac.x; t.y += ac.y; t.z += ac.z; t.w += ac.w;                   \
        dst[(c)*128 + dt] = t;
        MERGE_ST(0,a0) MERGE_ST(1,a1) MERGE_ST(2,a2) MERGE_ST(3,a3)
        MERGE_ST(4,a4) MERGE_ST(5,a5) MERGE_ST(6,a6) MERGE_ST(7,a7)
        MERGE_ST(8,a8) MERGE_ST(9,a9)
#undef MERGE_ST
    }
    // row j (=tid) = 2i+h -> combine the two waves of that half.
    if (tid < 128) {
        const int i2 = tid >> 1, h2 = tid & 1;
        norms[rows0 + tid] = ns[(2*h2)*64 + i2] + ns[(2*h2+1)*64 + i2];
    }
    if (tid < 16) counts[blockIdx.x * 16 + tid] = lc[tid];
}

// ---- kernel 2: reduce 1024 partial copies -> 8 partial copies ------------
// 320 blocks = 40 col-chunks x 8 copy-chunks; each block: 128 cols x 128
// copies. (Round-2 lesson: keep >=300 blocks — a 40-block variant was
// latency-bound on 40 CUs and cost +47 us.)

__global__ __launch_bounds__(256) void k_red(const float* __restrict__ part,
                                             float* __restrict__ psum8) {
    __shared__ float m[128];
    const int t   = threadIdx.x;
    const int col = t & 127, kh = t >> 7;
    const int cc  = blockIdx.x % 40;
    const int kc  = blockIdx.x / 40;
    const int e   = cc * 128 + col;

    const float* base = part + (size_t)(kc * 128 + kh * 64) * SUMSTRIDE + e;
    float s0=0.f, s1=0.f, s2=0.f, s3=0.f;
    for (int j = 0; j < 64; j += 4) {        // 4-way ILP over 64 copies
        s0 += base[(size_t)(j + 0) * SUMSTRIDE];
        s1 += base[(size_t)(j + 1) * SUMSTRIDE];
        s2 += base[(size_t)(j + 2) * SUMSTRIDE];
        s3 += base[(size_t)(j + 3) * SUMSTRIDE];
    }
    float s = (s0 + s1) + (s2 + s3);
    if (kh) m[col] = s;
    __syncthreads();
    if (!kh) psum8[kc * SUMSTRIDE + e] = s + m[col];
}

// ---- kernel 3: psum8 -> p2 (prototypes*2), wide-parallel -----------------
// 64 blocks x 256 threads (replaces the old single-block k_pp bubble).
// Blocks 0..39: 128 consecutive elements of the [c][dim] layout; the class
// c = b>>2 is block-uniform, and each block redundantly reduces its own
// class count from counts[1024][16] (4 KB of L2-hot reads — free).
// Blocks 40..63 zero-pad classes 10..15. ||p||^2 moved to k_main preamble.
// Every block self-contained: safe under rocprof dispatch replay.

__global__ __launch_bounds__(256) void k_pp2(const float* __restrict__ psum8,
                                             const int* __restrict__ counts,
                                             float* __restrict__ p2,
                                             float* __restrict__ out) {
    __shared__ int tmp[256];
    const int t = threadIdx.x;
    const int b = blockIdx.x;

    if (b >= 40) {                                // zero-pad classes 10..15
        if (t < 128) p2[5120 + (b - 40) * 128 + t] = 0.f;
        return;
    }
    if (b == 0 && t == 0) out[0] = 0.f;           // loss accumulator

    const int c = b >> 2;                         // block-uniform class
    {
        int sc = 0;
        for (int j = t; j < 1024; j += 256) sc += counts[j * 16 + c];
        tmp[t] = sc;
    }
    __syncthreads();
    if (t < 64) tmp[t] += tmp[t + 64] + tmp[t + 128] + tmp[t + 192];
    __syncthreads();
    if (t < 8)  tmp[t] += tmp[t + 8] + tmp[t + 16] + tmp[t + 24] + tmp[t + 32]
                        + tmp[t + 40] + tmp[t + 48] + tmp[t + 56];
    __syncthreads();
    if (t == 0) tmp[0] += tmp[1] + tmp[2] + tmp[3] + tmp[4] + tmp[5] + tmp[6]
                        + tmp[7];
    __syncthreads();
    const float cntf = (float)tmp[0];

    if (t < 128) {
        const int e = b * 128 + t;
        float ss = 0.f;
#pragma unroll
        for (int j = 0; j < 8; ++j) ss += psum8[j * SUMSTRIDE + e];
        p2[e] = 2.f * ss / cntf;                  // same div form as before
    }
}

// ---- kernel 4: distances + logits + log-softmax + loss -------------------
// One wave per 16-row tile; MFMA 16x16x32 bf16 for the 2*e.p cross term.
// A-operand from the L3-resident bf16 copy; exact fp32 row norms from
// k_seg. ||p||^2 computed in the fragment-build preamble (verified path
// from round 2). Logit stores non-temporal (write-once, keep out of L3).
// A-frag: lane holds row (lane&15), k = (lane>>4)*8 + j   [verified layout]
// C/D:    lane holds col (lane&15), rows (lane>>4)*4 + reg [verified layout]

__global__ __launch_bounds__(256, 2) void k_main(const ushort* __restrict__ E16,
                                                 const float* __restrict__ norms,
                                                 const int* __restrict__ L,
                                                 const float* __restrict__ p2,
                                                 float* __restrict__ out) {
    const int tid  = threadIdx.x;
    const int wid  = tid >> 6, lane = tid & 63;
    const int c16  = lane & 15, quad = lane >> 4;

    // B fragments (prototypes as bf16) + ||p||^2, built once per wave.
    // Lane covers dims kt*32 + quad*8 .. +7 for kt=0..15; the 4 quads cover
    // all 512 dims -> reduce ss over quad (shfl 16,32). Exact fp32.
    short8 bf[16];
    float ss = 0.f;
    const float4* P = (const float4*)p2;
#pragma unroll
    for (int kt = 0; kt < 16; ++kt) {
        float4 a = P[c16 * 128 + kt * 8 + quad * 2];
        float4 b = P[c16 * 128 + kt * 8 + quad * 2 + 1];
        ss += a.x*a.x + a.y*a.y + a.z*a.z + a.w*a.w
            + b.x*b.x + b.y*b.y + b.z*b.z + b.w*b.w;
        bf[kt] = pack8(a, b);
    }
    ss += __shfl_xor(ss, 16);
    ss += __shfl_xor(ss, 32);
    const float pnc = 0.25f * ss;               // p2 = 2p -> ||p||^2 = ss/4

    float lossp = 0.f;
    const int gw = blockIdx.x * 4 + wid;            // 0..4095
    for (int t = gw; t < 8192; t += 4096) {
        const int tile  = 8191 - t;                 // reverse order: L3-friendly
        const int rbase = tile * 16;
        // row stride = 512 bf16 = 32 short8 units; frag kt at dims kt*32+quad*8
        const short8* A = (const short8*)(E16 + (size_t)(rbase + c16) * DIMS);
        const float nmine = norms[rbase + c16];     // lane j: norm of row (j&15)

        floatx4 acc = {0.f, 0.f, 0.f, 0.f};
#pragma unroll
        for (int kt = 0; kt < 16; ++kt) {
            acc = __builtin_amdgcn_mfma_f32_16x16x32_bf16(A[kt * 4 + quad],
                                                          bf[kt], acc, 0, 0, 0);
        }

#pragma unroll
        for (int i = 0; i < 4; ++i) {
            const int row = rbase + quad * 4 + i;
            const float nr = __shfl(nmine, quad * 4 + i); // norm of row
            float lg = acc[i] - nr - pnc;                  // = 2e.p - ||e||^2 - ||p||^2 = -d2
            lg = fminf(lg, 0.f);                           // reference clamps d2 >= 0
            float ml = (c16 < NC) ? lg : -3.0e38f;
            ml = fmaxf(ml, __shfl_xor(ml, 1));
            ml = fmaxf(ml, __shfl_xor(ml, 2));
            ml = fmaxf(ml, __shfl_xor(ml, 4));
            ml = fmaxf(ml, __shfl_xor(ml, 8));
            float ex = (c16 < NC) ? __expf(lg - ml) : 0.f;
            ex += __shfl_xor(ex, 1);
            ex += __shfl_xor(ex, 2);
            ex += __shfl_xor(ex, 4);
            ex += __shfl_xor(ex, 8);
            const float lse = ml + __logf(ex);
            if (c16 < NC)
                __builtin_nontemporal_store(lg, &out[1 + row * NC + c16]);
            const int lab = L[row];
            if (c16 == lab) lossp += lse - lg;
        }
    }

    lossp += __shfl_xor(lossp, 1);  lossp += __shfl_xor(lossp, 2);
    lossp += __shfl_xor(lossp, 4);  lossp += __shfl_xor(lossp, 8);
    lossp += __shfl_xor(lossp, 16); lossp += __shfl_xor(lossp, 32);
    __shared__ float ls[4];
    if (lane == 0) ls[wid] = lossp;
    __syncthreads();
    if (tid == 0)
        atomicAdd(out, (ls[0] + ls[1] + ls[2] + ls[3]) * (1.0f / (float)NROWS));
}

// ---- launch --------------------------------------------------------------

extern "C" void kernel_launch(void* const* d_in, const int* in_sizes, int n_in,
                              void* d_out, int out_size, void* d_ws, size_t ws_size,
                              hipStream_t stream) {
    const float* E = (const float*)d_in[0];
    const int*   L = (const int*)d_in[1];
    float* out = (float*)d_out;
    char* ws = (char*)d_ws;

    // ws layout (bytes):
    //   part   1024*5120*4 = 20971520   @ 0
    //   psum8     8*5120*4 =   163840   @ 20971520
    //   counts 1024*16*4   =    65536   @ 21135360
    //   p2     16*512*4    =    32768   @ 21200896
    //   norms  131072*4    =   524288   @ 21233664
    //   E16    131072*512*2=134217728   @ 21757952  (16B aligned)
    float* part   = (float*)ws;
    float* psum8  = (float*)(ws + 20971520);
    int*   counts = (int*)  (ws + 21135360);
    float* p2     = (float*)(ws + 21200896);
    float* norms  = (float*)(ws + 21233664);
    uint2* E16    = (uint2*)(ws + 21757952);

    k_seg <<<SEG_BLOCKS, 256, 0, stream>>>(E, L, part, counts, E16, norms);
    k_red <<<320,        256, 0, stream>>>(part, psum8);
    k_pp2 <<<64,         256, 0, stream>>>(psum8, counts, p2, out);
    k_main<<<1024,       256, 0, stream>>>((const ushort*)E16, norms, L, p2, out);
}